// Round 2
// baseline (287.363 us; speedup 1.0000x reference)
//
#include <hip/hip_runtime.h>

// Problem constants (from reference)
#define C_IN   8
#define HH     32
#define WW     32
#define C_OUT  32
#define KK     4
#define SS     2
#define PP     1
#define HO     16
#define WO     16
#define IN_FEAT  8192   // C_IN*HH*WW
#define OUT_FEAT 8192   // C_OUT*HO*WO
// W_mat elements = 8192*8192 = 67108864; float4 count = 16777216

// clang vector type usable with __builtin_nontemporal_store
typedef float v4f __attribute__((ext_vector_type(4)));

// ---------------------------------------------------------------------------
// Kernel 1: write W_mat (Toeplitz matrix of the conv), 268.4 MB, write-bound.
// Each thread writes one float4 (4 consecutive columns, same (c_in,h) row).
// W_mat[row, col]: row = c_out*256 + ho*16 + wo ; col = c_in*1024 + h*32 + w
// value = weight[c_out, c_in, kh, kw] with kh = h - (2*ho - 1), kw = w - (2*wo - 1)
//         if 0<=kh<4 && 0<=kw<4, else 0.
// ---------------------------------------------------------------------------
__global__ __launch_bounds__(256) void wmat_kernel(const float* __restrict__ weight,
                                                   float* __restrict__ wmat) {
    const int idx = blockIdx.x * 256 + threadIdx.x;   // float4 index
    const int row = idx >> 11;                        // 2048 float4 per row
    const int col = (idx & 2047) << 2;                // first of 4 columns

    const int c_out = row >> 8;
    const int ho    = (row >> 4) & 15;
    const int wo    = row & 15;

    const int c_in  = col >> 10;
    const int h     = (col >> 5) & 31;
    const int w0    = col & 31;                       // 0,4,...,28 (4 cols stay in-row)

    const int kh  = h  - (ho * 2 - 1);
    const int kwb = w0 - (wo * 2 - 1);

    float v[4] = {0.f, 0.f, 0.f, 0.f};
    if ((unsigned)kh < (unsigned)KK) {
        const float* wrow = weight + ((c_out * C_IN + c_in) * (KK * KK) + kh * KK);
#pragma unroll
        for (int j = 0; j < 4; ++j) {
            const int kw = kwb + j;
            if ((unsigned)kw < (unsigned)KK) v[j] = wrow[kw];
        }
    }
    v4f o = { v[0], v[1], v[2], v[3] };
    // 256 MB stream write, never re-read on device -> nontemporal
    __builtin_nontemporal_store(o, reinterpret_cast<v4f*>(wmat) + idx);
}

// ---------------------------------------------------------------------------
// Kernel 2: forward interval conv bounds + bias_backsub.
// Back-substitution (Mp@l + Mm@u + bias) is algebraically identical to the
// forward bound, so the tighten is an identity — compute the conv once.
// 8192 threads, each does one (c_out,ho,wo): 128 taps.
// ---------------------------------------------------------------------------
__global__ __launch_bounds__(256) void bounds_kernel(const float* __restrict__ bounds,
                                                     const float* __restrict__ weight,
                                                     const float* __restrict__ bias,
                                                     float* __restrict__ out_bounds,
                                                     float* __restrict__ bias_bs) {
    const int t = blockIdx.x * 256 + threadIdx.x;     // 0..8191
    const int c_out = t >> 8;
    const int ho    = (t >> 4) & 15;
    const int wo    = t & 15;

    const float* lptr = bounds;                       // bounds[0]
    const float* uptr = bounds + C_IN * HH * WW;      // bounds[1]

    float lo = 0.f, up = 0.f;
    for (int ci = 0; ci < C_IN; ++ci) {
#pragma unroll
        for (int kh = 0; kh < KK; ++kh) {
            const int h = ho * SS - PP + kh;
            if ((unsigned)h >= (unsigned)HH) continue;
#pragma unroll
            for (int kw = 0; kw < KK; ++kw) {
                const int w = wo * SS - PP + kw;
                if ((unsigned)w >= (unsigned)WW) continue;
                const float wv = weight[(c_out * C_IN + ci) * (KK * KK) + kh * KK + kw];
                const float wp = fmaxf(wv, 0.f);
                const float wm = fminf(wv, 0.f);
                const int off = ci * (HH * WW) + h * WW + w;
                const float lv = lptr[off];
                const float uv = uptr[off];
                lo = fmaf(wp, lv, lo); lo = fmaf(wm, uv, lo);
                up = fmaf(wp, uv, up); up = fmaf(wm, lv, up);
            }
        }
    }
    const float b = bias[c_out];
    out_bounds[t]            = lo + b;   // lower  [32,16,16]
    out_bounds[OUT_FEAT + t] = up + b;   // upper
    bias_bs[t] = b;                      // repeat_interleave(bias, 256)
}

extern "C" void kernel_launch(void* const* d_in, const int* in_sizes, int n_in,
                              void* d_out, int out_size, void* d_ws, size_t ws_size,
                              hipStream_t stream) {
    const float* bounds = (const float*)d_in[0];   // [2,8,32,32]
    const float* weight = (const float*)d_in[1];   // [32,8,4,4]
    const float* bias   = (const float*)d_in[2];   // [32]
    // d_in[3] = assignment (unused by forward)

    float* out     = (float*)d_out;
    float* wmat    = out + 2 * OUT_FEAT;                      // after out_bounds (16384)
    float* bias_bs = out + 2 * OUT_FEAT + (size_t)OUT_FEAT * IN_FEAT;

    // W_mat: 16777216 float4 stores, 256 threads/block -> 65536 blocks
    wmat_kernel<<<65536, 256, 0, stream>>>(weight, wmat);
    // bounds + bias_backsub: 8192 threads
    bounds_kernel<<<32, 256, 0, stream>>>(bounds, weight, bias, out, bias_bs);
}

// Round 3
// 279.312 us; speedup vs baseline: 1.0288x; 1.0288x over previous
//
#include <hip/hip_runtime.h>

// Problem constants (from reference)
#define C_IN   8
#define HH     32
#define WW     32
#define C_OUT  32
#define KK     4
#define SS     2
#define PP     1
#define HO     16
#define WO     16
#define IN_FEAT  8192   // C_IN*HH*WW
#define OUT_FEAT 8192   // C_OUT*HO*WO
// W_mat elements = 8192*8192 = 67108864 -> 16777216 float4

#define WMAT_V4      16777216
#define WMAT_BLOCKS  16384
#define WMAT_ITERS   4        // WMAT_BLOCKS*256*WMAT_ITERS == WMAT_V4

// ---------------------------------------------------------------------------
// Kernel 1: write W_mat (Toeplitz matrix of the conv), 268.4 MB, write-bound.
// Grid-stride, 4 float4 per thread, PLAIN stores (nt killed write-combining:
// R2 measured ~1 TB/s with nt vs 6.4 TB/s for the harness's plain-store fill).
// W_mat[row, col]: row = c_out*256 + ho*16 + wo ; col = c_in*1024 + h*32 + w
// value = weight[c_out, c_in, kh, kw] with kh = h - (2*ho - 1), kw = w - (2*wo - 1)
//         if 0<=kh<4 && 0<=kw<4, else 0.
// ---------------------------------------------------------------------------
__global__ __launch_bounds__(256) void wmat_kernel(const float* __restrict__ weight,
                                                   float4* __restrict__ wmat) {
    const int stride = WMAT_BLOCKS * 256;
    int idx = blockIdx.x * 256 + threadIdx.x;
#pragma unroll
    for (int it = 0; it < WMAT_ITERS; ++it, idx += stride) {
        const int row = idx >> 11;                    // 2048 float4 per row
        const int col = (idx & 2047) << 2;            // first of 4 columns

        const int c_out = row >> 8;
        const int ho    = (row >> 4) & 15;
        const int wo    = row & 15;

        const int c_in  = col >> 10;
        const int h     = (col >> 5) & 31;
        const int w0    = col & 31;                   // 0,4,...,28 (row of 32 floats)

        const int kh  = h  - (ho * 2 - 1);
        const int kwb = w0 - (wo * 2 - 1);

        float v[4] = {0.f, 0.f, 0.f, 0.f};
        if ((unsigned)kh < (unsigned)KK) {
            const float* wrow = weight + ((c_out * C_IN + c_in) * (KK * KK) + kh * KK);
#pragma unroll
            for (int j = 0; j < 4; ++j) {
                const int kw = kwb + j;
                if ((unsigned)kw < (unsigned)KK) v[j] = wrow[kw];
            }
        }
        wmat[idx] = make_float4(v[0], v[1], v[2], v[3]);
    }
}

// ---------------------------------------------------------------------------
// Kernel 2: forward interval conv bounds + bias_backsub.
// Back-substitution (Mp@l + Mm@u + bias) is algebraically identical to the
// forward bound, so the tighten is an identity — compute the conv once.
// 8192 threads, each does one (c_out,ho,wo): 128 taps.
// ---------------------------------------------------------------------------
__global__ __launch_bounds__(256) void bounds_kernel(const float* __restrict__ bounds,
                                                     const float* __restrict__ weight,
                                                     const float* __restrict__ bias,
                                                     float* __restrict__ out_bounds,
                                                     float* __restrict__ bias_bs) {
    const int t = blockIdx.x * 256 + threadIdx.x;     // 0..8191
    const int c_out = t >> 8;
    const int ho    = (t >> 4) & 15;
    const int wo    = t & 15;

    const float* lptr = bounds;                       // bounds[0]
    const float* uptr = bounds + C_IN * HH * WW;      // bounds[1]

    float lo = 0.f, up = 0.f;
    for (int ci = 0; ci < C_IN; ++ci) {
#pragma unroll
        for (int kh = 0; kh < KK; ++kh) {
            const int h = ho * SS - PP + kh;
            if ((unsigned)h >= (unsigned)HH) continue;
#pragma unroll
            for (int kw = 0; kw < KK; ++kw) {
                const int w = wo * SS - PP + kw;
                if ((unsigned)w >= (unsigned)WW) continue;
                const float wv = weight[(c_out * C_IN + ci) * (KK * KK) + kh * KK + kw];
                const float wp = fmaxf(wv, 0.f);
                const float wm = fminf(wv, 0.f);
                const int off = ci * (HH * WW) + h * WW + w;
                const float lv = lptr[off];
                const float uv = uptr[off];
                lo = fmaf(wp, lv, lo); lo = fmaf(wm, uv, lo);
                up = fmaf(wp, uv, up); up = fmaf(wm, lv, up);
            }
        }
    }
    const float b = bias[c_out];
    out_bounds[t]            = lo + b;   // lower  [32,16,16]
    out_bounds[OUT_FEAT + t] = up + b;   // upper
    bias_bs[t] = b;                      // repeat_interleave(bias, 256)
}

extern "C" void kernel_launch(void* const* d_in, const int* in_sizes, int n_in,
                              void* d_out, int out_size, void* d_ws, size_t ws_size,
                              hipStream_t stream) {
    const float* bounds = (const float*)d_in[0];   // [2,8,32,32]
    const float* weight = (const float*)d_in[1];   // [32,8,4,4]
    const float* bias   = (const float*)d_in[2];   // [32]
    // d_in[3] = assignment (unused by forward)

    float* out     = (float*)d_out;
    float* wmat    = out + 2 * OUT_FEAT;                      // after out_bounds (16384)
    float* bias_bs = out + 2 * OUT_FEAT + (size_t)OUT_FEAT * IN_FEAT;

    wmat_kernel<<<WMAT_BLOCKS, 256, 0, stream>>>(weight, (float4*)wmat);
    bounds_kernel<<<32, 256, 0, stream>>>(bounds, weight, bias, out, bias_bs);
}

// Round 4
// 264.857 us; speedup vs baseline: 1.0850x; 1.0546x over previous
//
#include <hip/hip_runtime.h>

// Problem constants (from reference)
#define C_IN   8
#define HH     32
#define WW     32
#define C_OUT  32
#define KK     4
#define SS     2
#define PP     1
#define HO     16
#define WO     16
#define IN_FEAT  8192   // C_IN*HH*WW
#define OUT_FEAT 8192   // C_OUT*HO*WO
// W_mat elements = 8192*8192 = 67108864 -> 16777216 float4 (exactly)

// ---------------------------------------------------------------------------
// Kernel 1: stream zeros over the whole W_mat region (268.4 MB).
// Structurally identical to the harness fill kernel (which sustains the
// device's best pure-write rate): grid-stride, 1 float4/iter, no compute.
// The ~1M nonzeros (1.6% of entries) are patched afterwards by kernel 2.
// ---------------------------------------------------------------------------
__global__ __launch_bounds__(256) void zero_wmat(float4* __restrict__ wmat) {
    const int stride = 16384 * 256;
    int idx = blockIdx.x * 256 + threadIdx.x;
#pragma unroll
    for (int it = 0; it < 4; ++it, idx += stride)
        wmat[idx] = make_float4(0.f, 0.f, 0.f, 0.f);
}

// ---------------------------------------------------------------------------
// Kernel 2: one wave per Toeplitz row (8192 rows).
//  - scatters the <=128 nonzeros of W_mat row (tap (ci,kh,kw) -> col)
//  - computes the interval-conv bound for that row from the same taps
//    (back-substitution == forward interval conv, so tighten is identity)
//  - lane 0 writes out_bounds lower/upper and bias_backsub.
// row = c_out*256 + ho*16 + wo ; col = ci*1024 + h*32 + w,
// h = 2*ho - 1 + kh, w = 2*wo - 1 + kw, valid iff h,w in [0,32).
// ---------------------------------------------------------------------------
__global__ __launch_bounds__(256) void scatter_bounds(const float* __restrict__ bounds,
                                                      const float* __restrict__ weight,
                                                      const float* __restrict__ bias,
                                                      float* __restrict__ wmat,
                                                      float* __restrict__ out_bounds,
                                                      float* __restrict__ bias_bs) {
    const int row  = (blockIdx.x * 256 + threadIdx.x) >> 6;  // 0..8191
    const int lane = threadIdx.x & 63;

    const int c_out = row >> 8;
    const int ho    = (row >> 4) & 15;
    const int wo    = row & 15;

    const float* lptr = bounds;             // bounds[0]
    const float* uptr = bounds + IN_FEAT;   // bounds[1]

    float lo = 0.f, up = 0.f;
#pragma unroll
    for (int s = 0; s < 2; ++s) {
        const int t  = lane + 64 * s;       // tap 0..127
        const int ci = t >> 4;
        const int kh = (t >> 2) & 3;
        const int kw = t & 3;
        const int h  = ho * SS - PP + kh;
        const int w  = wo * SS - PP + kw;
        if ((unsigned)h < (unsigned)HH && (unsigned)w < (unsigned)WW) {
            const float wv  = weight[(c_out * C_IN + ci) * (KK * KK) + kh * KK + kw];
            const int   col = ci * (HH * WW) + h * WW + w;
            wmat[(size_t)row * IN_FEAT + col] = wv;   // patch the nonzero
            const float lv = lptr[col];
            const float uv = uptr[col];
            const float wp = fmaxf(wv, 0.f);
            const float wm = fminf(wv, 0.f);
            lo = fmaf(wp, lv, fmaf(wm, uv, lo));
            up = fmaf(wp, uv, fmaf(wm, lv, up));
        }
    }
    // wave64 shuffle reduction
#pragma unroll
    for (int off = 32; off; off >>= 1) {
        lo += __shfl_down(lo, off, 64);
        up += __shfl_down(up, off, 64);
    }
    if (lane == 0) {
        const float b = bias[c_out];
        out_bounds[row]            = lo + b;  // lower  [32,16,16]
        out_bounds[OUT_FEAT + row] = up + b;  // upper
        bias_bs[row] = b;                     // repeat_interleave(bias, 256)
    }
}

extern "C" void kernel_launch(void* const* d_in, const int* in_sizes, int n_in,
                              void* d_out, int out_size, void* d_ws, size_t ws_size,
                              hipStream_t stream) {
    const float* bounds = (const float*)d_in[0];   // [2,8,32,32]
    const float* weight = (const float*)d_in[1];   // [32,8,4,4]
    const float* bias   = (const float*)d_in[2];   // [32]
    // d_in[3] = assignment (unused by forward)

    float* out     = (float*)d_out;
    float* wmat    = out + 2 * OUT_FEAT;                      // after out_bounds (16384)
    float* bias_bs = out + 2 * OUT_FEAT + (size_t)OUT_FEAT * IN_FEAT;

    // 1) stream-zero W_mat: 16777216 float4 = 16384 blocks * 256 thr * 4
    zero_wmat<<<16384, 256, 0, stream>>>((float4*)wmat);
    // 2) patch nonzeros + bounds + bias (stream-ordered after the zero pass):
    //    8192 rows, one wave each, 4 waves/block -> 2048 blocks
    scatter_bounds<<<2048, 256, 0, stream>>>(bounds, weight, bias, wmat, out, bias_bs);
}

// Round 5
// 262.944 us; speedup vs baseline: 1.0929x; 1.0073x over previous
//
#include <hip/hip_runtime.h>

// Problem constants (from reference)
#define C_IN   8
#define HH     32
#define WW     32
#define C_OUT  32
#define KK     4
#define SS     2
#define PP     1
#define HO     16
#define WO     16
#define IN_FEAT  8192   // C_IN*HH*WW
#define OUT_FEAT 8192   // C_OUT*HO*WO

// ---------------------------------------------------------------------------
// Fully fused: one wave per Toeplitz row (8192 rows, 64 lanes each).
// The wave streams its whole 32 KB W_mat row as coalesced float4 stores
// (32 iters x 1 KB/wave), patching the <=128 nonzeros inline — zeros and
// nonzeros leave in ONE write stream (no scatter RMW, no 2nd launch).
// Common path per float4: window test (~4 VALU) + store; the weight-select
// path runs on ~3% of slots. The same taps feed the interval-conv bound
// (back-substitution == forward interval conv, so the tighten is identity),
// wave shuffle-reduced; lane 0 writes out_bounds lower/upper + bias_backsub.
//
// Layout: row = c_out*256 + ho*16 + wo ; col = ci*1024 + h*32 + w
// nonzero iff h = 2*ho-1+kh, w = 2*wo-1+kw with kh,kw in [0,4), h,w in [0,32);
// value = weight[c_out, ci, kh, kw]. Clipped taps = conv zero-padding, drop.
// ---------------------------------------------------------------------------
__global__ __launch_bounds__(256) void fused_row_kernel(const float* __restrict__ bounds,
                                                        const float* __restrict__ weight,
                                                        const float* __restrict__ bias,
                                                        float* __restrict__ wmat,
                                                        float* __restrict__ out_bounds,
                                                        float* __restrict__ bias_bs) {
    const int gid  = blockIdx.x * 256 + threadIdx.x;
    const int row  = gid >> 6;                 // 0..8191
    const int lane = threadIdx.x & 63;

    const int c_out = row >> 8;
    const int ho    = (row >> 4) & 15;
    const int wo    = row & 15;
    const int hs    = ho * SS - PP;            // first h of the kernel window
    const int ws    = wo * SS - PP;            // first w of the kernel window

    const float* lptr = bounds;                // bounds[0]
    const float* uptr = bounds + IN_FEAT;      // bounds[1]
    float* __restrict__ rout = wmat + (size_t)row * IN_FEAT;

    float lo = 0.f, up = 0.f;

#pragma unroll 8
    for (int it = 0; it < 32; ++it) {
        const int col0 = it * 256 + lane * 4;  // this lane's float4 base col
        const int ci   = col0 >> 10;
        const int h    = (col0 >> 5) & 31;
        const int w0   = col0 & 31;

        const int kh  = h  - hs;               // valid iff in [0,4)
        const int kwb = w0 - ws;               // kw of element j is kwb+j

        float4 v = make_float4(0.f, 0.f, 0.f, 0.f);
        if ((unsigned)kh < (unsigned)KK && kwb >= -3 && kwb <= 3) {
            const float4 wr = *reinterpret_cast<const float4*>(
                weight + ((c_out * C_IN + ci) * (KK * KK) + kh * KK));
            float* vp = &v.x;
#pragma unroll
            for (int j = 0; j < 4; ++j) {
                const int kw = kwb + j;
                if ((unsigned)kw < (unsigned)KK) {
                    const float wv = (kw == 0) ? wr.x : (kw == 1) ? wr.y
                                   : (kw == 2) ? wr.z : wr.w;
                    vp[j] = wv;
                    const int col = col0 + j;
                    const float lv = lptr[col];
                    const float uv = uptr[col];
                    const float wp = fmaxf(wv, 0.f);
                    const float wm = fminf(wv, 0.f);
                    lo = fmaf(wp, lv, fmaf(wm, uv, lo));
                    up = fmaf(wp, uv, fmaf(wm, lv, up));
                }
            }
        }
        *reinterpret_cast<float4*>(rout + col0) = v;   // coalesced 1KB/wave store
    }

    // wave64 shuffle reduction of the bound partials
#pragma unroll
    for (int off = 32; off; off >>= 1) {
        lo += __shfl_down(lo, off, 64);
        up += __shfl_down(up, off, 64);
    }
    if (lane == 0) {
        const float b = bias[c_out];
        out_bounds[row]            = lo + b;   // lower  [32,16,16]
        out_bounds[OUT_FEAT + row] = up + b;   // upper
        bias_bs[row] = b;                      // repeat_interleave(bias, 256)
    }
}

extern "C" void kernel_launch(void* const* d_in, const int* in_sizes, int n_in,
                              void* d_out, int out_size, void* d_ws, size_t ws_size,
                              hipStream_t stream) {
    const float* bounds = (const float*)d_in[0];   // [2,8,32,32]
    const float* weight = (const float*)d_in[1];   // [32,8,4,4]
    const float* bias   = (const float*)d_in[2];   // [32]
    // d_in[3] = assignment (unused by forward)

    float* out     = (float*)d_out;
    float* wmat    = out + 2 * OUT_FEAT;                      // after out_bounds (16384)
    float* bias_bs = out + 2 * OUT_FEAT + (size_t)OUT_FEAT * IN_FEAT;

    // 8192 rows x 1 wave = 524288 threads -> 2048 blocks of 256
    fused_row_kernel<<<2048, 256, 0, stream>>>(bounds, weight, bias, wmat, out, bias_bs);
}

// Round 6
// 259.719 us; speedup vs baseline: 1.1064x; 1.0124x over previous
//
#include <hip/hip_runtime.h>

// Problem constants (from reference)
#define C_IN   8
#define HH     32
#define WW     32
#define C_OUT  32
#define KK     4
#define SS     2
#define PP     1
#define HO     16
#define WO     16
#define IN_FEAT  8192   // C_IN*HH*WW
#define OUT_FEAT 8192   // C_OUT*HO*WO

// ---------------------------------------------------------------------------
// One wave per Toeplitz row (8192 rows, 64 lanes).
// Stream the 32 KB row as 32 x 1KB coalesced float4 stores. The branch
// "does this 8-row h-block contain the conv window" depends only on
// (row, iteration) -> wave-uniform; readfirstlane forces it into an SGPR so
// the compiler emits s_cbranch and the MISS path is fill-kernel shaped:
// store pre-zeroed quad, advance pointer. Lane-level tap work runs only in
// the <=2 hit h-blocks per ci (<=16 of 32 iterations).
// Bounds (back-substitution == forward interval conv, tighten is identity)
// are computed AFTER the stream from 2 taps/lane + wave shuffle-reduce, so
// their cache loads overlap the store drain.
//
// Layout: row = c_out*256 + ho*16 + wo ; col = ci*1024 + h*32 + w
// nonzero iff h = 2*ho-1+kh, w = 2*wo-1+kw, kh,kw in [0,4), h,w in [0,32);
// value = weight[c_out, ci, kh, kw].
// ---------------------------------------------------------------------------
__global__ __launch_bounds__(256) void fused_row_kernel(const float* __restrict__ bounds,
                                                        const float* __restrict__ weight,
                                                        const float* __restrict__ bias,
                                                        float* __restrict__ wmat,
                                                        float* __restrict__ out_bounds,
                                                        float* __restrict__ bias_bs) {
    const int gid  = blockIdx.x * 256 + threadIdx.x;
    const int row  = gid >> 6;                 // 0..8191 (wave-uniform)
    const int lane = threadIdx.x & 63;

    const int c_out = row >> 8;
    const int ho    = (row >> 4) & 15;
    const int wo    = row & 15;
    const int hs    = ho * SS - PP;            // window h start (may be -1)
    const int ws    = wo * SS - PP;            // window w start (may be -1)

    // per-lane constants for the stream loop
    const int  lh   = lane >> 3;               // h offset within an 8-row block
    const int  w0   = (lane & 7) * 4;          // float4 w base (0..28)
    const int  kwb  = w0 - ws;                 // kw of element j is kwb+j
    const bool whit = (kwb >= -3) & (kwb <= 3);

    // wave-uniform h-block hit mask (forced scalar)
    unsigned hbmask = 0;
    {
        const int loh = hs > 0 ? hs : 0;
        const int hih = (hs + 3) < 31 ? (hs + 3) : 31;
#pragma unroll
        for (int hb = 0; hb < 4; ++hb)
            if (hb * 8 <= hih && loh <= hb * 8 + 7) hbmask |= 1u << hb;
    }
    hbmask = __builtin_amdgcn_readfirstlane(hbmask);

    const float4 zero4 = make_float4(0.f, 0.f, 0.f, 0.f);
    float4* __restrict__ rp = reinterpret_cast<float4*>(wmat + (size_t)row * IN_FEAT) + lane;
    const float* __restrict__ wco = weight + c_out * (C_IN * KK * KK);

    // ---- stream the 32 KB row ----
    for (int ci = 0; ci < C_IN; ++ci) {
#pragma unroll
        for (int hb = 0; hb < 4; ++hb, rp += 64) {
            if (hbmask & (1u << hb)) {         // s_cbranch: skip on miss blocks
                float4 v = zero4;
                const int kh = hb * 8 + lh - hs;
                if (((unsigned)kh < (unsigned)KK) & whit) {
                    const float* wb = wco + ci * (KK * KK) + kh * KK;
                    float* vp = &v.x;
#pragma unroll
                    for (int j = 0; j < 4; ++j) {
                        const int kw = kwb + j;
                        if ((unsigned)kw < (unsigned)KK) vp[j] = wb[kw];
                    }
                }
                *rp = v;
            } else {
                *rp = zero4;                   // fill-kernel shaped common path
            }
        }
    }

    // ---- bounds + bias (2 taps per lane over the 128-tap stencil) ----
    const float* lptr = bounds;                // bounds[0]
    const float* uptr = bounds + IN_FEAT;      // bounds[1]
    float lo = 0.f, up = 0.f;
#pragma unroll
    for (int s = 0; s < 2; ++s) {
        const int t  = lane + 64 * s;          // tap 0..127
        const int ci = t >> 4;
        const int kh = (t >> 2) & 3;
        const int kw = t & 3;
        const int h  = hs + kh;
        const int w  = ws + kw;
        if ((unsigned)h < (unsigned)HH && (unsigned)w < (unsigned)WW) {
            const float wv  = wco[ci * (KK * KK) + kh * KK + kw];
            const int   col = ci * (HH * WW) + h * WW + w;
            const float lv = lptr[col];
            const float uv = uptr[col];
            const float wp = fmaxf(wv, 0.f);
            const float wm = fminf(wv, 0.f);
            lo = fmaf(wp, lv, fmaf(wm, uv, lo));
            up = fmaf(wp, uv, fmaf(wm, lv, up));
        }
    }
#pragma unroll
    for (int off = 32; off; off >>= 1) {
        lo += __shfl_down(lo, off, 64);
        up += __shfl_down(up, off, 64);
    }
    if (lane == 0) {
        const float b = bias[c_out];
        out_bounds[row]            = lo + b;   // lower  [32,16,16]
        out_bounds[OUT_FEAT + row] = up + b;   // upper
        bias_bs[row] = b;                      // repeat_interleave(bias, 256)
    }
}

extern "C" void kernel_launch(void* const* d_in, const int* in_sizes, int n_in,
                              void* d_out, int out_size, void* d_ws, size_t ws_size,
                              hipStream_t stream) {
    const float* bounds = (const float*)d_in[0];   // [2,8,32,32]
    const float* weight = (const float*)d_in[1];   // [32,8,4,4]
    const float* bias   = (const float*)d_in[2];   // [32]
    // d_in[3] = assignment (unused by forward)

    float* out     = (float*)d_out;
    float* wmat    = out + 2 * OUT_FEAT;                      // after out_bounds (16384)
    float* bias_bs = out + 2 * OUT_FEAT + (size_t)OUT_FEAT * IN_FEAT;

    // 8192 rows x 1 wave = 524288 threads -> 2048 blocks of 256
    fused_row_kernel<<<2048, 256, 0, stream>>>(bounds, weight, bias, wmat, out, bias_bs);
}